// Round 1
// baseline (3203.114 us; speedup 1.0000x reference)
//
#include <hip/hip_runtime.h>
#include <math.h>

#define Lr   32
#define Hh   128
#define HP2  130
#define CELLW (Hh * HP2)   // 16640 floats per cell
#define NEPS 1e-8f

// Transpose W1[cell][k][m] (k<128, m<130) -> Wt[cell][m][k] so the RNN kernel's
// weight loads are lane-coalesced (lane k reads consecutive floats at fixed m).
__global__ __launch_bounds__(256)
void transpose_w(const float* __restrict__ W1, float* __restrict__ Wt) {
    const int cell = blockIdx.x;
    const float* src = W1 + (size_t)cell * CELLW;
    float* dst = Wt + (size_t)cell * CELLW;
    for (int idx = threadIdx.x; idx < CELLW; idx += 256) {
        const int m = idx >> 7;     // idx = m*128 + k
        const int k = idx & 127;
        dst[idx] = src[k * HP2 + m];
    }
}

// 256 blocks, each owns 2 batch elements and runs the full 1024-cell sequence.
// 256 threads: kp = t&63 owns output pair (2kp, 2kp+1); half = t>>6 is the
// 4-way m-split of the 130-long dot product.
__global__ __launch_bounds__(256, 2)
void rnn2d(const float* __restrict__ samples,
           const float* __restrict__ Wt,
           const float* __restrict__ b1,
           const float* __restrict__ Wf,
           const float* __restrict__ bfv,
           float* __restrict__ out)
{
    __shared__ float hv[2][Lr][Hh];      // vertical hidden state per raw column (32 KB)
    __shared__ float hh[2][Hh];          // horizontal hidden state
    __shared__ float2 inp2[HP2];         // inp[m] for (b0, b1)
    __shared__ float pA[4][64], pB[4][64], pC[4][64], pD[4][64];  // m-split partials

    const int t    = threadIdx.x;
    const int kp   = t & 63;
    const int half = t >> 6;
    const int b0   = blockIdx.x * 2;

    for (int idx = t; idx < 2 * Lr * Hh; idx += 256) ((float*)hv)[idx] = 0.f;
    float lp = 0.f;
    __syncthreads();

    for (int i = 0; i < Lr; ++i) {
        const int dir = (i & 1) ? -1 : 1;
        int c = (i & 1) ? (Lr - 1) : 0;
        for (int j = 0; j < Lr; ++j, c += dir) {
            const int cell = i * Lr + c;

            // ---- stage 1: build input vector (both batch elements) ----
            if (t < HP2) {
                float x0, x1;
                if (t >= 2) {
                    const int m = t - 2;
                    const float hh0 = (j == 0) ? 0.f : hh[0][m];
                    const float hh1 = (j == 0) ? 0.f : hh[1][m];
                    x0 = hh0 + hv[0][c][m];
                    x1 = hh1 + hv[1][c][m];
                } else {
                    const float xh0 = (j == 0) ? 0.f : samples[(b0 + 0) * (Lr * Lr) + i * Lr + (c - dir)];
                    const float xh1 = (j == 0) ? 0.f : samples[(b0 + 1) * (Lr * Lr) + i * Lr + (c - dir)];
                    const float xv0 = (i == 0) ? 0.f : samples[(b0 + 0) * (Lr * Lr) + (i - 1) * Lr + c];
                    const float xv1 = (i == 0) ? 0.f : samples[(b0 + 1) * (Lr * Lr) + (i - 1) * Lr + c];
                    if (t == 0) { x0 = xh0 + xv0;       x1 = xh1 + xv1; }
                    else        { x0 = 2.f - xh0 - xv0; x1 = 2.f - xh1 - xv1; }
                }
                inp2[t] = make_float2(x0, x1);
            }
            __syncthreads();

            // ---- stage 2: matvec partials (weights coalesced, L2-streamed) ----
            const float* wbase = Wt + (size_t)cell * CELLW + 2 * kp;
            float a00 = 0.f, a01 = 0.f, a10 = 0.f, a11 = 0.f;
#define MV(MS, MC)                                                        \
            _Pragma("unroll")                                             \
            for (int p = 0; p < (MC); ++p) {                              \
                const int m = (MS) + p;                                   \
                const float2 w = *(const float2*)(wbase + (size_t)m * Hh);\
                const float2 v = inp2[m];                                 \
                a00 = fmaf(w.x, v.x, a00); a01 = fmaf(w.x, v.y, a01);     \
                a10 = fmaf(w.y, v.x, a10); a11 = fmaf(w.y, v.y, a11);     \
            }
            if      (half == 0) { MV(0, 33) }
            else if (half == 1) { MV(33, 33) }
            else if (half == 2) { MV(66, 32) }
            else                { MV(98, 32) }
#undef MV
            pA[half][kp] = a00; pB[half][kp] = a01;
            pC[half][kp] = a10; pD[half][kp] = a11;
            __syncthreads();

            // ---- stage 3: finalize h (wave0 -> batch0, wave1 -> batch1) ----
            if (half < 2) {
                float s0, s1;
                if (half == 0) {
                    s0 = pA[0][kp] + pA[1][kp] + pA[2][kp] + pA[3][kp];
                    s1 = pC[0][kp] + pC[1][kp] + pC[2][kp] + pC[3][kp];
                } else {
                    s0 = pB[0][kp] + pB[1][kp] + pB[2][kp] + pB[3][kp];
                    s1 = pD[0][kp] + pD[1][kp] + pD[2][kp] + pD[3][kp];
                }
                const float2 bv = *(const float2*)(b1 + cell * Hh + 2 * kp);
                const float h0 = tanhf(s0 + 2.f * bv.x);
                const float h1 = tanhf(s1 + 2.f * bv.y);
                hh[half][2 * kp]     = h0;
                hh[half][2 * kp + 1] = h1;
                hv[half][c][2 * kp]     = h0;
                hv[half][c][2 * kp + 1] = h1;
                // head: dot(h, Wf[cell]) via wave reduction
                const float2 wv = *(const float2*)(Wf + cell * Hh + 2 * kp);
                float f = h0 * wv.x + h1 * wv.y;
                f += __shfl_down(f, 32);
                f += __shfl_down(f, 16);
                f += __shfl_down(f, 8);
                f += __shfl_down(f, 4);
                f += __shfl_down(f, 2);
                f += __shfl_down(f, 1);
                if (kp == 0) {
                    const float z    = f + bfv[cell];
                    const float xhat = 1.f / (1.f + expf(-z));
                    const float mcur = samples[(b0 + half) * (Lr * Lr) + i * Lr + c];
                    lp += logf(xhat + NEPS) * mcur + logf(1.f - xhat + NEPS) * (1.f - mcur);
                }
            }
            __syncthreads();   // hh/hv visible to next cell's stage 1
        }
    }
    if (t == 0 || t == 64) out[b0 + half] = lp;
}

extern "C" void kernel_launch(void* const* d_in, const int* in_sizes, int n_in,
                              void* d_out, int out_size, void* d_ws, size_t ws_size,
                              hipStream_t stream) {
    const float* samples = (const float*)d_in[0];
    const float* W1      = (const float*)d_in[1];
    const float* b1      = (const float*)d_in[2];
    const float* Wf      = (const float*)d_in[3];
    const float* bf      = (const float*)d_in[4];
    float* outp = (float*)d_out;
    float* Wt   = (float*)d_ws;   // needs 1024*128*130*4 = 68.2 MB

    transpose_w<<<1024, 256, 0, stream>>>(W1, Wt);
    rnn2d<<<256, 256, 0, stream>>>(samples, Wt, b1, Wf, bf, outp);
}

// Round 2
// 2441.577 us; speedup vs baseline: 1.3119x; 1.3119x over previous
//
#include <hip/hip_runtime.h>
#include <math.h>

#define Lr   32
#define Hh   128
#define HP2  130
#define MPAD 132                  // m padded to 4*33 so all 4 waves run uniform 33-loops
#define CELLW (MPAD * Hh)         // 16896 floats per padded cell
#define NEPS 1e-8f

// Transpose W1[cell][k][m] (k<128, m<130) -> Wt[cell][m][k], m padded to 132
// with zeros, so weight loads are lane-coalesced 512 B rows.
__global__ __launch_bounds__(256)
void transpose_w(const float* __restrict__ W1, float* __restrict__ Wt) {
    const int cell = blockIdx.x;
    const float* src = W1 + (size_t)cell * (Hh * HP2);
    float* dst = Wt + (size_t)cell * CELLW;
    for (int idx = threadIdx.x; idx < CELLW; idx += 256) {
        const int m = idx >> 7;     // idx = m*128 + k
        const int k = idx & 127;
        dst[idx] = (m < HP2) ? src[k * HP2 + m] : 0.f;
    }
}

__device__ __forceinline__ int cell_of(int s) {
    const int i = s >> 5, jj = s & 31;
    const int c = (i & 1) ? (Lr - 1 - jj) : jj;
    return i * Lr + c;
}

// 256 blocks × 2 batch elements; 256 threads: kp=t&63 owns k-pair (2kp,2kp+1),
// half=t>>6 is the 4-way m-split. Weights + b1/Wf for cell s+1 are prefetched
// into registers while cell s computes; no other vmcnt traffic in the loop.
__global__ __launch_bounds__(256, 1)
void rnn2d(const float* __restrict__ samples,
           const float* __restrict__ Wt,
           const float* __restrict__ b1,
           const float* __restrict__ Wf,
           const float* __restrict__ bfv,
           float* __restrict__ out)
{
    __shared__ float hv[2][Lr][Hh];      // 32 KB vertical hidden states
    __shared__ float hh[2][Hh];          // horizontal hidden state
    __shared__ float2 inp2[MPAD];        // inp[m] for (b0,b1); [130],[131] stay 0
    __shared__ float pA[4][64], pB[4][64], pC[4][64], pD[4][64];
    __shared__ float smp[2][Lr * Lr];    // 8 KB staged samples

    const int t    = threadIdx.x;
    const int kp   = t & 63;
    const int half = t >> 6;
    const int MS   = half * 33;
    const int b0   = blockIdx.x * 2;
    const float* wcellbase = Wt + (size_t)MS * Hh + 2 * kp;

    for (int idx = t; idx < 2 * Lr * Hh; idx += 256) ((float*)hv)[idx] = 0.f;
    if (t < 2) inp2[HP2 + t] = make_float2(0.f, 0.f);
    for (int idx = t; idx < 2 * Lr * Lr; idx += 256) {
        const int b = idx >> 10, pos = idx & 1023;
        smp[b][pos] = samples[(size_t)(b0 + b) * (Lr * Lr) + pos];
    }
    float lp = 0.f;
    __syncthreads();

    float2 wA[33], wB[33];
    float2 bvA, bvB, wvA, wvB;

#define LOADW(S, BUF, BV, WV)                                              \
    {                                                                      \
        const int cc_ = cell_of(S);                                        \
        const float* p_ = wcellbase + (size_t)cc_ * CELLW;                 \
        _Pragma("unroll")                                                  \
        for (int q_ = 0; q_ < 33; ++q_)                                    \
            BUF[q_] = *(const float2*)(p_ + q_ * Hh);                      \
        BV = *(const float2*)(b1 + cc_ * Hh + 2 * kp);                     \
        WV = *(const float2*)(Wf + cc_ * Hh + 2 * kp);                     \
    }

#define PROCESS(S, BUF, BV, WV)                                            \
    {                                                                      \
        const int i_ = (S) >> 5, j_ = (S) & 31;                            \
        const int dir_ = (i_ & 1) ? -1 : 1;                                \
        const int c_ = (i_ & 1) ? (Lr - 1 - j_) : j_;                      \
        const int cell_ = i_ * Lr + c_;                                    \
        /* stage 1: build input vector from LDS only */                    \
        if (t < HP2) {                                                     \
            float x0, x1;                                                  \
            if (t >= 2) {                                                  \
                const int m_ = t - 2;                                      \
                const float h0_ = (j_ == 0) ? 0.f : hh[0][m_];             \
                const float h1_ = (j_ == 0) ? 0.f : hh[1][m_];             \
                x0 = h0_ + hv[0][c_][m_];                                  \
                x1 = h1_ + hv[1][c_][m_];                                  \
            } else {                                                       \
                const float xh0 = (j_ == 0) ? 0.f : smp[0][i_ * Lr + (c_ - dir_)]; \
                const float xh1 = (j_ == 0) ? 0.f : smp[1][i_ * Lr + (c_ - dir_)]; \
                const float xv0 = (i_ == 0) ? 0.f : smp[0][(i_ - 1) * Lr + c_];    \
                const float xv1 = (i_ == 0) ? 0.f : smp[1][(i_ - 1) * Lr + c_];    \
                if (t == 0) { x0 = xh0 + xv0;       x1 = xh1 + xv1; }      \
                else        { x0 = 2.f - xh0 - xv0; x1 = 2.f - xh1 - xv1; }\
            }                                                              \
            inp2[t] = make_float2(x0, x1);                                 \
        }                                                                  \
        __syncthreads();                                                   \
        /* stage 2: matvec from registers */                               \
        float a00 = 0.f, a01 = 0.f, a10 = 0.f, a11 = 0.f;                  \
        _Pragma("unroll")                                                  \
        for (int q_ = 0; q_ < 33; ++q_) {                                  \
            const float2 w_ = BUF[q_];                                     \
            const float2 v_ = inp2[MS + q_];                               \
            a00 = fmaf(w_.x, v_.x, a00); a01 = fmaf(w_.x, v_.y, a01);      \
            a10 = fmaf(w_.y, v_.x, a10); a11 = fmaf(w_.y, v_.y, a11);      \
        }                                                                  \
        pA[half][kp] = a00; pB[half][kp] = a01;                            \
        pC[half][kp] = a10; pD[half][kp] = a11;                            \
        __syncthreads();                                                   \
        /* stage 3: finalize h, head, log-prob */                          \
        if (half < 2) {                                                    \
            float s0_, s1_;                                                \
            if (half == 0) {                                               \
                s0_ = pA[0][kp] + pA[1][kp] + pA[2][kp] + pA[3][kp];       \
                s1_ = pC[0][kp] + pC[1][kp] + pC[2][kp] + pC[3][kp];       \
            } else {                                                       \
                s0_ = pB[0][kp] + pB[1][kp] + pB[2][kp] + pB[3][kp];       \
                s1_ = pD[0][kp] + pD[1][kp] + pD[2][kp] + pD[3][kp];       \
            }                                                              \
            const float h0_ = tanhf(s0_ + 2.f * (BV).x);                   \
            const float h1_ = tanhf(s1_ + 2.f * (BV).y);                   \
            hh[half][2 * kp]     = h0_;                                    \
            hh[half][2 * kp + 1] = h1_;                                    \
            hv[half][c_][2 * kp]     = h0_;                                \
            hv[half][c_][2 * kp + 1] = h1_;                                \
            float f_ = h0_ * (WV).x + h1_ * (WV).y;                        \
            f_ += __shfl_down(f_, 32);                                     \
            f_ += __shfl_down(f_, 16);                                     \
            f_ += __shfl_down(f_, 8);                                      \
            f_ += __shfl_down(f_, 4);                                      \
            f_ += __shfl_down(f_, 2);                                      \
            f_ += __shfl_down(f_, 1);                                      \
            if (kp == 0) {                                                 \
                const float z_    = f_ + bfv[cell_];                       \
                const float xhat_ = 1.f / (1.f + expf(-z_));               \
                const float mc_   = smp[half][i_ * Lr + c_];               \
                lp += logf(xhat_ + NEPS) * mc_                             \
                    + logf(1.f - xhat_ + NEPS) * (1.f - mc_);              \
            }                                                              \
        }                                                                  \
        __syncthreads();                                                   \
    }

    LOADW(0, wA, bvA, wvA);
    for (int s = 0; s < Lr * Lr; s += 2) {
        LOADW(s + 1, wB, bvB, wvB);
        PROCESS(s, wA, bvA, wvA);
        if (s + 2 < Lr * Lr) LOADW(s + 2, wA, bvA, wvA);
        PROCESS(s + 1, wB, bvB, wvB);
    }
#undef LOADW
#undef PROCESS

    if (t == 0 || t == 64) out[b0 + half] = lp;
}

extern "C" void kernel_launch(void* const* d_in, const int* in_sizes, int n_in,
                              void* d_out, int out_size, void* d_ws, size_t ws_size,
                              hipStream_t stream) {
    const float* samples = (const float*)d_in[0];
    const float* W1      = (const float*)d_in[1];
    const float* b1      = (const float*)d_in[2];
    const float* Wf      = (const float*)d_in[3];
    const float* bf      = (const float*)d_in[4];
    float* outp = (float*)d_out;
    float* Wt   = (float*)d_ws;   // needs 1024*132*128*4 = 69.2 MB

    transpose_w<<<1024, 256, 0, stream>>>(W1, Wt);
    rnn2d<<<256, 256, 0, stream>>>(samples, Wt, b1, Wf, bf, outp);
}

// Round 3
// 1895.665 us; speedup vs baseline: 1.6897x; 1.2880x over previous
//
#include <hip/hip_runtime.h>
#include <hip/hip_fp16.h>
#include <math.h>

#define Lr   32
#define Hh   128
#define HP2  130
#define MPAD 132                  // m padded to 4*33 so all 4 waves run uniform 33-loops
#define CELLW (MPAD * Hh)         // 16896 halfs per padded cell
#define NEPS 1e-8f

// Barrier that does NOT drain vmcnt: in-flight global->register weight
// prefetches survive. lgkmcnt(0) gives cross-wave LDS visibility; "memory"
// clobber stops the compiler moving LDS ops (or sinking prefetch loads)
// across it. Safe because no global stores / LDS-bound vmem occur in-loop.
__device__ __forceinline__ void bar_lds() {
    asm volatile("s_waitcnt lgkmcnt(0)\n\ts_barrier" ::: "memory");
}

// W1[cell][k][m] (k<128, m<130, fp32) -> Wt[cell][m][k] (fp16, m padded to 132
// with zeros). LDS-staged so both global read and global write are coalesced.
// Tile row stride 130 halfs (not 128) so the scattered LDS half-writes spread
// across banks instead of a 64-way pileup.
#define TROW 130
__global__ __launch_bounds__(256)
void transpose_w(const float* __restrict__ W1, __half* __restrict__ Wt) {
    __shared__ __half tile[MPAD * TROW];
    const int cell = blockIdx.x;
    const float* src = W1 + (size_t)cell * (Hh * HP2);
    __half* dst = Wt + (size_t)cell * CELLW;
    for (int idx = threadIdx.x; idx < Hh * HP2; idx += 256) {
        const int k = idx / HP2, m = idx - k * HP2;   // src idx = k*130 + m
        tile[m * TROW + k] = __float2half(src[idx]);
    }
    for (int idx = threadIdx.x; idx < 2 * Hh; idx += 256)
        tile[(HP2 + (idx >> 7)) * TROW + (idx & 127)] = __float2half(0.f);
    __syncthreads();
    for (int idx = threadIdx.x; idx < CELLW; idx += 256) {
        const int m = idx >> 7, k = idx & 127;
        dst[idx] = tile[m * TROW + k];
    }
}

__device__ __forceinline__ int cell_of(int s) {
    const int i = s >> 5, jj = s & 31;
    const int c = (i & 1) ? (Lr - 1 - jj) : jj;
    return i * Lr + c;
}

// 256 blocks x 2 batch elements; 256 threads: kp=t&63 owns k-pair (2kp,2kp+1),
// half=t>>6 is the 4-way m-split. fp16 weights + fp32 b1/Wf for cell s+1
// prefetched into registers while cell s computes; the ONLY vmem in the loop.
__global__ __launch_bounds__(256, 1)
void rnn2d(const float* __restrict__ samples,
           const __half* __restrict__ Wt,
           const float* __restrict__ b1,
           const float* __restrict__ Wf,
           const float* __restrict__ bfv,
           float* __restrict__ out)
{
    __shared__ float hv[2][Lr][Hh];      // 32 KB vertical hidden states
    __shared__ float hh[2][Hh];          // horizontal hidden state
    __shared__ float2 inp2[MPAD];        // inp[m] for (b0,b1); [130],[131] stay 0
    __shared__ float pA[4][64], pB[4][64], pC[4][64], pD[4][64];
    __shared__ float smp[2][Lr * Lr];    // 8 KB staged samples
    __shared__ float bfs[Lr * Lr];       // 4 KB staged head bias

    const int t    = threadIdx.x;
    const int kp   = t & 63;
    const int half = t >> 6;
    const int MS   = half * 33;
    const int b0   = blockIdx.x * 2;
    const __half* wcellbase = Wt + (size_t)MS * Hh + 2 * kp;

    for (int idx = t; idx < 2 * Lr * Hh; idx += 256) ((float*)hv)[idx] = 0.f;
    if (t < 2) inp2[HP2 + t] = make_float2(0.f, 0.f);
    for (int idx = t; idx < 2 * Lr * Lr; idx += 256) {
        const int b = idx >> 10, pos = idx & 1023;
        smp[b][pos] = samples[(size_t)(b0 + b) * (Lr * Lr) + pos];
    }
    for (int idx = t; idx < Lr * Lr; idx += 256) bfs[idx] = bfv[idx];
    float lp = 0.f;
    __syncthreads();

    __half2 wA[33], wB[33];
    float2 bvA, bvB, wvA, wvB;

#define LOADW(S, BUF, BV, WV)                                              \
    {                                                                      \
        const int cc_ = cell_of(S);                                        \
        const __half* p_ = wcellbase + (size_t)cc_ * CELLW;                \
        _Pragma("unroll")                                                  \
        for (int q_ = 0; q_ < 33; ++q_)                                    \
            BUF[q_] = *(const __half2*)(p_ + q_ * Hh);                     \
        BV = *(const float2*)(b1 + cc_ * Hh + 2 * kp);                     \
        WV = *(const float2*)(Wf + cc_ * Hh + 2 * kp);                     \
    }

#define PROCESS(S, BUF, BV, WV)                                            \
    {                                                                      \
        const int i_ = (S) >> 5, j_ = (S) & 31;                            \
        const int dir_ = (i_ & 1) ? -1 : 1;                                \
        const int c_ = (i_ & 1) ? (Lr - 1 - j_) : j_;                      \
        const int cell_ = i_ * Lr + c_;                                    \
        /* stage 1: build input vector from LDS only */                    \
        if (t < HP2) {                                                     \
            float x0, x1;                                                  \
            if (t >= 2) {                                                  \
                const int m_ = t - 2;                                      \
                const float h0_ = (j_ == 0) ? 0.f : hh[0][m_];             \
                const float h1_ = (j_ == 0) ? 0.f : hh[1][m_];             \
                x0 = h0_ + hv[0][c_][m_];                                  \
                x1 = h1_ + hv[1][c_][m_];                                  \
            } else {                                                       \
                const float xh0 = (j_ == 0) ? 0.f : smp[0][i_ * Lr + (c_ - dir_)]; \
                const float xh1 = (j_ == 0) ? 0.f : smp[1][i_ * Lr + (c_ - dir_)]; \
                const float xv0 = (i_ == 0) ? 0.f : smp[0][(i_ - 1) * Lr + c_];    \
                const float xv1 = (i_ == 0) ? 0.f : smp[1][(i_ - 1) * Lr + c_];    \
                if (t == 0) { x0 = xh0 + xv0;       x1 = xh1 + xv1; }      \
                else        { x0 = 2.f - xh0 - xv0; x1 = 2.f - xh1 - xv1; }\
            }                                                              \
            inp2[t] = make_float2(x0, x1);                                 \
        }                                                                  \
        bar_lds();                                                         \
        /* stage 2: matvec from registers (weights), LDS broadcast (inp) */\
        float a00 = 0.f, a01 = 0.f, a10 = 0.f, a11 = 0.f;                  \
        _Pragma("unroll")                                                  \
        for (int q_ = 0; q_ < 33; ++q_) {                                  \
            const float2 w_ = __half22float2(BUF[q_]);                     \
            const float2 v_ = inp2[MS + q_];                               \
            a00 = fmaf(w_.x, v_.x, a00); a01 = fmaf(w_.x, v_.y, a01);      \
            a10 = fmaf(w_.y, v_.x, a10); a11 = fmaf(w_.y, v_.y, a11);      \
        }                                                                  \
        pA[half][kp] = a00; pB[half][kp] = a01;                            \
        pC[half][kp] = a10; pD[half][kp] = a11;                            \
        bar_lds();                                                         \
        /* stage 3: finalize h, head, log-prob */                          \
        if (half < 2) {                                                    \
            float s0_, s1_;                                                \
            if (half == 0) {                                               \
                s0_ = pA[0][kp] + pA[1][kp] + pA[2][kp] + pA[3][kp];       \
                s1_ = pC[0][kp] + pC[1][kp] + pC[2][kp] + pC[3][kp];       \
            } else {                                                       \
                s0_ = pB[0][kp] + pB[1][kp] + pB[2][kp] + pB[3][kp];       \
                s1_ = pD[0][kp] + pD[1][kp] + pD[2][kp] + pD[3][kp];       \
            }                                                              \
            const float h0_ = tanhf(s0_ + 2.f * (BV).x);                   \
            const float h1_ = tanhf(s1_ + 2.f * (BV).y);                   \
            hh[half][2 * kp]     = h0_;                                    \
            hh[half][2 * kp + 1] = h1_;                                    \
            hv[half][c_][2 * kp]     = h0_;                                \
            hv[half][c_][2 * kp + 1] = h1_;                                \
            float f_ = h0_ * (WV).x + h1_ * (WV).y;                        \
            f_ += __shfl_down(f_, 32);                                     \
            f_ += __shfl_down(f_, 16);                                     \
            f_ += __shfl_down(f_, 8);                                      \
            f_ += __shfl_down(f_, 4);                                      \
            f_ += __shfl_down(f_, 2);                                      \
            f_ += __shfl_down(f_, 1);                                      \
            if (kp == 0) {                                                 \
                const float z_    = f_ + bfs[cell_];                       \
                const float xhat_ = 1.f / (1.f + expf(-z_));               \
                const float mc_   = smp[half][i_ * Lr + c_];               \
                lp += logf(xhat_ + NEPS) * mc_                             \
                    + logf(1.f - xhat_ + NEPS) * (1.f - mc_);              \
            }                                                              \
        }                                                                  \
        bar_lds();                                                         \
    }

    LOADW(0, wA, bvA, wvA);
    for (int s = 0; s < Lr * Lr; s += 2) {
        LOADW(s + 1, wB, bvB, wvB);
        PROCESS(s, wA, bvA, wvA);
        if (s + 2 < Lr * Lr) LOADW(s + 2, wA, bvA, wvA);
        PROCESS(s + 1, wB, bvB, wvB);
    }
#undef LOADW
#undef PROCESS

    if (t == 0 || t == 64) out[b0 + half] = lp;
}

extern "C" void kernel_launch(void* const* d_in, const int* in_sizes, int n_in,
                              void* d_out, int out_size, void* d_ws, size_t ws_size,
                              hipStream_t stream) {
    const float* samples = (const float*)d_in[0];
    const float* W1      = (const float*)d_in[1];
    const float* b1      = (const float*)d_in[2];
    const float* Wf      = (const float*)d_in[3];
    const float* bf      = (const float*)d_in[4];
    float* outp = (float*)d_out;
    __half* Wt  = (__half*)d_ws;   // needs 1024*132*128*2 = 34.6 MB

    transpose_w<<<1024, 256, 0, stream>>>(W1, Wt);
    rnn2d<<<256, 256, 0, stream>>>(samples, Wt, b1, Wf, bf, outp);
}

// Round 4
// 1394.953 us; speedup vs baseline: 2.2962x; 1.3589x over previous
//
#include <hip/hip_runtime.h>
#include <hip/hip_fp16.h>
#include <math.h>

#define Lr   32
#define Hh   128
#define HP2  130
#define MPAD 132                  // m padded to 4*33 so all 4 waves run uniform 33-loops
#define CELLW (MPAD * Hh)         // 16896 halfs per padded cell
#define NEPS 1e-8f

// Barrier that does NOT drain vmcnt: in-flight global->register weight
// prefetches survive across it. lgkmcnt(0) gives cross-wave LDS visibility.
__device__ __forceinline__ void bar_lds() {
    asm volatile("s_waitcnt lgkmcnt(0)\n\ts_barrier" ::: "memory");
}

// W1[cell][k][m] (k<128, m<130, fp32) -> Wt[cell][m][k] (fp16, m padded to 132
// with zeros). LDS-staged so global read and write are both coalesced.
#define TROW 130
__global__ __launch_bounds__(256)
void transpose_w(const float* __restrict__ W1, __half* __restrict__ Wt) {
    __shared__ __half tile[MPAD * TROW];
    const int cell = blockIdx.x;
    const float* src = W1 + (size_t)cell * (Hh * HP2);
    __half* dst = Wt + (size_t)cell * CELLW;
    for (int idx = threadIdx.x; idx < Hh * HP2; idx += 256) {
        const int k = idx / HP2, m = idx - k * HP2;
        tile[m * TROW + k] = __float2half(src[idx]);
    }
    for (int idx = threadIdx.x; idx < 2 * Hh; idx += 256)
        tile[(HP2 + (idx >> 7)) * TROW + (idx & 127)] = __float2half(0.f);
    __syncthreads();
    for (int idx = threadIdx.x; idx < CELLW; idx += 256) {
        const int m = idx >> 7, k = idx & 127;
        dst[idx] = tile[m * TROW + k];
    }
}

__device__ __forceinline__ int cell_of(int s) {
    const int i = s >> 5, jj = s & 31;
    const int c = (i & 1) ? (Lr - 1 - jj) : jj;
    return i * Lr + c;
}

// 512 blocks x 1 batch element (2 blocks/CU for latency interleave).
// 256 threads: kp=t&63, half=t>>6 (4-way m-split of the 130-dot).
// Waves 0/1 = "state" (h -> hv + next-cell inp2, the recurrence-critical path).
// Waves 2/3 = "head"  (redundant h, wf-dot + shuffle reduce; sigmoid/log tail
// deferred one cell onto lane 128 during the next matvec phase).
__global__ __launch_bounds__(256, 2)
void rnn2d(const float* __restrict__ samples,
           const __half* __restrict__ Wt,
           const float* __restrict__ b1,
           const float* __restrict__ Wf,
           const float* __restrict__ bfv,
           float* __restrict__ out)
{
    __shared__ float hv[Lr][Hh];         // 16 KB vertical hidden state
    __shared__ float inp2[MPAD];         // current-cell input vector; [130..131]=0
    __shared__ float prt[8][64];         // matvec partials: [mc][kp]=k even, [4+mc][kp]=k odd
    __shared__ float smp[Lr * Lr];       // 4 KB staged samples (this batch element)
    __shared__ float bfs[Lr * Lr];       // 4 KB staged head bias
    __shared__ float fpart[2];           // head-dot wave partials (prev cell)

    const int t    = threadIdx.x;
    const int kp   = t & 63;
    const int half = t >> 6;
    const int MS   = half * 33;
    const int u    = t & 127;            // k index owned in epilogue
    const int b    = blockIdx.x;
    const __half* wcellbase = Wt + (size_t)MS * Hh + 2 * kp;

    for (int idx = t; idx < Lr * Hh; idx += 256) ((float*)hv)[idx] = 0.f;
    for (int idx = t; idx < MPAD; idx += 256) inp2[idx] = (idx == 1) ? 2.f : 0.f;
    for (int idx = t; idx < Lr * Lr; idx += 256) {
        smp[idx] = samples[(size_t)b * (Lr * Lr) + idx];
        bfs[idx] = bfv[idx];
    }
    float lp = 0.f;
    __syncthreads();

    __half2 wA[33], wB[33];
    float bvA, bvB, wvA, wvB;

#define LOADW(S, BUF, BV, WV)                                              \
    {                                                                      \
        const int cc_ = cell_of(S);                                        \
        const __half* p_ = wcellbase + (size_t)cc_ * CELLW;                \
        _Pragma("unroll")                                                  \
        for (int q_ = 0; q_ < 33; ++q_)                                    \
            BUF[q_] = *(const __half2*)(p_ + q_ * Hh);                     \
        BV = b1[cc_ * Hh + u];                                             \
        WV = Wf[cc_ * Hh + u];                                             \
    }

#define LPFIN(CC)                                                          \
    {                                                                      \
        const float z_    = fpart[0] + fpart[1] + bfs[CC];                 \
        const float xhat_ = 1.f / (1.f + expf(-z_));                       \
        const float mc_   = smp[CC];                                       \
        lp += logf(xhat_ + NEPS) * mc_                                     \
            + logf(1.f - xhat_ + NEPS) * (1.f - mc_);                      \
    }

#define PROCESS(S, BUF, BV, WV)                                            \
    {                                                                      \
        const int i_ = (S) >> 5, j_ = (S) & 31;                            \
        const int c_ = (i_ & 1) ? (Lr - 1 - j_) : j_;                      \
        /* phase A: deferred lp tail for cell S-1 (lane 128 only) */       \
        if (t == 128 && (S) > 0) { LPFIN(cell_of((S) - 1)); }              \
        /* phase A: matvec from prefetched registers, inp2 broadcast */    \
        float a0 = 0.f, a1 = 0.f;                                          \
        _Pragma("unroll")                                                  \
        for (int q_ = 0; q_ < 33; ++q_) {                                  \
            const float2 w_ = __half22float2(BUF[q_]);                     \
            const float v_  = inp2[MS + q_];                               \
            a0 = fmaf(w_.x, v_, a0); a1 = fmaf(w_.y, v_, a1);              \
        }                                                                  \
        prt[half][kp] = a0; prt[4 + half][kp] = a1;                        \
        bar_lds();                                                         \
        /* phase B: epilogue, specialized by wave group */                 \
        {                                                                  \
            const int r_  = (u & 1) * 4, cl_ = u >> 1;                     \
            const float s_ = prt[r_][cl_] + prt[r_ + 1][cl_]               \
                           + prt[r_ + 2][cl_] + prt[r_ + 3][cl_];          \
            const float h_ = tanhf(s_ + 2.f * (BV));                       \
            if (t < 128) {                                                 \
                /* state: hv + next-cell input vector */                   \
                hv[c_][u] = h_;                                            \
                if ((S) + 1 < Lr * Lr) {                                   \
                    const int sn_ = (S) + 1;                               \
                    const int in_ = sn_ >> 5, jn_ = sn_ & 31;              \
                    const int cn_ = (in_ & 1) ? (Lr - 1 - jn_) : jn_;      \
                    const float hvn_ = (cn_ == c_) ? h_ : hv[cn_][u];      \
                    inp2[u + 2] = ((jn_ == 0) ? 0.f : h_) + hvn_;          \
                    if (u < 2) {                                           \
                        const float xh_ = (jn_ == 0) ? 0.f : smp[i_ * Lr + c_];          \
                        const float xv_ = (in_ == 0) ? 0.f : smp[(in_ - 1) * Lr + cn_];  \
                        inp2[u] = (u == 0) ? (xh_ + xv_) : (2.f - xh_ - xv_);            \
                    }                                                      \
                }                                                          \
            } else {                                                       \
                /* head: wf-dot + per-wave shuffle reduce */               \
                float f_ = h_ * (WV);                                      \
                f_ += __shfl_down(f_, 32);                                 \
                f_ += __shfl_down(f_, 16);                                 \
                f_ += __shfl_down(f_, 8);                                  \
                f_ += __shfl_down(f_, 4);                                  \
                f_ += __shfl_down(f_, 2);                                  \
                f_ += __shfl_down(f_, 1);                                  \
                if (kp == 0) fpart[half - 2] = f_;                         \
            }                                                              \
        }                                                                  \
        bar_lds();                                                         \
    }

    LOADW(0, wA, bvA, wvA);
    for (int s = 0; s < Lr * Lr; s += 2) {
        LOADW(s + 1, wB, bvB, wvB);
        PROCESS(s, wA, bvA, wvA);
        if (s + 2 < Lr * Lr) LOADW(s + 2, wA, bvA, wvA);
        PROCESS(s + 1, wB, bvB, wvB);
    }
#undef LOADW
#undef PROCESS

    // tail: lp for the last cell, then output
    if (t == 128) {
        LPFIN(cell_of(Lr * Lr - 1));
        out[b] = lp;
    }
#undef LPFIN
}

extern "C" void kernel_launch(void* const* d_in, const int* in_sizes, int n_in,
                              void* d_out, int out_size, void* d_ws, size_t ws_size,
                              hipStream_t stream) {
    const float* samples = (const float*)d_in[0];
    const float* W1      = (const float*)d_in[1];
    const float* b1      = (const float*)d_in[2];
    const float* Wf      = (const float*)d_in[3];
    const float* bf      = (const float*)d_in[4];
    float* outp = (float*)d_out;
    __half* Wt  = (__half*)d_ws;   // needs 1024*132*128*2 = 34.6 MB

    transpose_w<<<1024, 256, 0, stream>>>(W1, Wt);
    rnn2d<<<512, 256, 0, stream>>>(samples, Wt, b1, Wf, bf, outp);
}